// Round 4
// baseline (941.051 us; speedup 1.0000x reference)
//
#include <hip/hip_runtime.h>

// MultiScaleRetention. Inputs f32, output f32.
// B=2 T=2048 D=2048 H=8 DK=256 DV=512 C=64, N_chunks=32.
// R4: bf16-DMA GEMMs (weights pre-converted per-GEMM) + low-LDS retention
// (direct global MFMA frags, kT global tensor, conflict-free LDS strides).
// ws (u16): xb[8.4M] q[8.4M] k[8.4M] kT[8.4M] v[16.8M] o[16.8M] = 134.4MB
//   wt(weight tmp) aliases kT pre-rotary; Wg->kT post-retention; Wo->xb;
//   g aliases q+k; on aliases v.

typedef unsigned short u16;
typedef unsigned int u32;
typedef short bf16x8 __attribute__((ext_vector_type(8)));
typedef short s16x4 __attribute__((ext_vector_type(4)));
typedef float f32x4 __attribute__((ext_vector_type(4)));
typedef u32 u32x2 __attribute__((ext_vector_type(2)));
typedef u32 u32x4 __attribute__((ext_vector_type(4)));

typedef __attribute__((address_space(3))) u32 lds_u32;
typedef __attribute__((address_space(1))) const u32 gbl_u32;

__device__ __forceinline__ float bf2f(u16 u) {
    union { u32 i; float f; } x; x.i = ((u32)u) << 16; return x.f;
}
__device__ __forceinline__ u16 f2bf(float f) {
    union { float f; u32 i; } x; x.f = f;
    u32 u = x.i;
    u += 0x7fffu + ((u >> 16) & 1u);   // RNE (finite only)
    return (u16)(u >> 16);
}
__device__ __forceinline__ f32x4 mfma16(bf16x8 a, bf16x8 b, f32x4 c) {
    return __builtin_amdgcn_mfma_f32_16x16x32_bf16(a, b, c, 0, 0, 0);
}
// async global->LDS, 16B/lane; lds base must be wave-uniform (dest=base+lane*16)
__device__ __forceinline__ void gload16(const u16* g, u16* lds) {
    __builtin_amdgcn_global_load_lds((gbl_u32*)(unsigned long long)g,
                                     (lds_u32*)(u32)(unsigned long long)lds, 16, 0, 0);
}

// ---------------------------------------------------------------------------
// f32 -> bf16 bulk convert. 8 elems/thread. grid = elems/2048.
// ---------------------------------------------------------------------------
__global__ __launch_bounds__(256)
void cvt_bf16(const float* __restrict__ src, u16* __restrict__ dst)
{
    size_t i = ((size_t)blockIdx.x * 256 + threadIdx.x) * 8;
    f32x4 a = *(const f32x4*)(src + i);
    f32x4 b = *(const f32x4*)(src + i + 4);
    bf16x8 r;
#pragma unroll
    for (int j = 0; j < 4; j++) { r[j] = (short)f2bf(a[j]); r[j + 4] = (short)f2bf(b[j]); }
    *(bf16x8*)(dst + i) = r;
}

// ---------------------------------------------------------------------------
// NT GEMM: C[M][N] = A[M][K](bf16) @ B[N][K](bf16)^T, fp32 acc, C bf16/f32.
// grid=(N/128, M/128), block=256. 128x128 tile, BK=64, global_load_lds DMA.
// ---------------------------------------------------------------------------
template<bool CF32>
__global__ __launch_bounds__(256, 2)
void gemm_bt(const u16* __restrict__ A, const u16* __restrict__ Bm,
             void* __restrict__ Cv, int N, int K)
{
    __shared__ u16 Ab[128 * 64];
    __shared__ u16 Bb[128 * 64];
    const int tid = threadIdx.x;
    const int lane = tid & 63, wave = tid >> 6;
    const int quad = lane >> 4, l16 = lane & 15;
    const int tn = blockIdx.x, tm = blockIdx.y;
    const int wr = wave >> 1, wc = wave & 1;

    f32x4 acc[4][4];
#pragma unroll
    for (int i = 0; i < 4; i++)
#pragma unroll
        for (int j = 0; j < 4; j++) acc[i][j] = (f32x4){0.f, 0.f, 0.f, 0.f};

    const u16* Abase = A + (size_t)tm * 128 * K;
    const u16* Bbase = Bm + (size_t)tn * 128 * K;
    const int rsub = lane >> 3, csub = (lane & 7) * 8;

    for (int k0 = 0; k0 < K; k0 += 64) {
        __syncthreads();                        // readers of prev tile done
#pragma unroll
        for (int i = 0; i < 4; i++) {
            int chunk = wave * 4 + i;           // 16 chunks of 8 rows x 64 cols
            int r = chunk * 8 + rsub;
            gload16(Abase + (size_t)r * K + k0 + csub, Ab + chunk * 512);
            gload16(Bbase + (size_t)r * K + k0 + csub, Bb + chunk * 512);
        }
        __syncthreads();                        // DMA drained (vmcnt0 at barrier)
#pragma unroll
        for (int kc = 0; kc < 2; kc++) {
            bf16x8 af[4], bfr[4];
#pragma unroll
            for (int mt = 0; mt < 4; mt++)
                af[mt] = *(const bf16x8*)(Ab + (wr * 64 + mt * 16 + l16) * 64 + kc * 32 + quad * 8);
#pragma unroll
            for (int nt = 0; nt < 4; nt++)
                bfr[nt] = *(const bf16x8*)(Bb + (wc * 64 + nt * 16 + l16) * 64 + kc * 32 + quad * 8);
#pragma unroll
            for (int mt = 0; mt < 4; mt++)
#pragma unroll
                for (int nt = 0; nt < 4; nt++)
                    acc[mt][nt] = mfma16(af[mt], bfr[nt], acc[mt][nt]);
        }
    }
    const int row0 = tm * 128 + wr * 64 + quad * 4;
    const int col0 = tn * 128 + wc * 64 + l16;
#pragma unroll
    for (int mt = 0; mt < 4; mt++)
#pragma unroll
        for (int nt = 0; nt < 4; nt++)
#pragma unroll
            for (int r = 0; r < 4; r++) {
                size_t idx = (size_t)(row0 + mt * 16 + r) * N + col0 + nt * 16;
                if constexpr (CF32) ((float*)Cv)[idx] = acc[mt][nt][r];
                else                ((u16*)Cv)[idx]   = f2bf(acc[mt][nt][r]);
            }
}

// ---------------------------------------------------------------------------
// Rotary (in place) on q (* DK^-0.5) and k; also emits kT[b,h,d,t] (bf16)
// via LDS tile transpose. grid = 512 (= b2*h8*32 t-tiles of 64), block 256.
// ---------------------------------------------------------------------------
__global__ __launch_bounds__(256)
void rotary_qk(u16* __restrict__ q, u16* __restrict__ k, u16* __restrict__ kT)
{
    __shared__ u16 kt[64 * 264];
    const int bx = blockIdx.x;
    const int tile = bx & 31, h = (bx >> 5) & 7, b = bx >> 8;
    const int t0 = tile * 64;
    const int tid = threadIdx.x;
    const int tl = tid >> 2;             // 0..63 local row
    const int j0 = (tid & 3) * 32;       // pair-index range [j0, j0+32)
    const size_t rowbase = (size_t)(b * 2048 + t0 + tl) * 2048 + h * 256;
    const float tpos = (float)(t0 + tl);

#pragma unroll
    for (int i = 0; i < 4; i++) {
        int j = j0 + i * 8;
        bf16x8 x1 = *(const bf16x8*)(q + rowbase + j);
        bf16x8 x2 = *(const bf16x8*)(q + rowbase + j + 128);
        bf16x8 y1 = *(const bf16x8*)(k + rowbase + j);
        bf16x8 y2 = *(const bf16x8*)(k + rowbase + j + 128);
        bf16x8 o1, o2, p1, p2;
#pragma unroll
        for (int e = 0; e < 8; e++) {
            float inv = expf((-9.210340371976184f / 128.f) * (float)(j + e));
            float ang = tpos * inv;
            float sv = sinf(ang), cv = cosf(ang);
            float a = bf2f((u16)x1[e]), bb = bf2f((u16)x2[e]);
            o1[e] = (short)f2bf((a * cv - bb * sv) * 0.0625f);
            o2[e] = (short)f2bf((bb * cv + a * sv) * 0.0625f);
            float e1 = bf2f((u16)y1[e]), e2 = bf2f((u16)y2[e]);
            p1[e] = (short)f2bf(e1 * cv - e2 * sv);
            p2[e] = (short)f2bf(e2 * cv + e1 * sv);
        }
        *(bf16x8*)(q + rowbase + j)       = o1;
        *(bf16x8*)(q + rowbase + j + 128) = o2;
        *(bf16x8*)(k + rowbase + j)       = p1;
        *(bf16x8*)(k + rowbase + j + 128) = p2;
        *(bf16x8*)(kt + tl * 264 + j)       = p1;
        *(bf16x8*)(kt + tl * 264 + j + 128) = p2;
    }
    __syncthreads();
    // phase 2: thread d writes kT row d, cols t0..t0+63
    const int d = tid;
    u16* dst = kT + ((size_t)((b * 8 + h) * 256 + d)) * 2048 + t0;
#pragma unroll
    for (int gidx = 0; gidx < 8; gidx++) {
        bf16x8 w;
#pragma unroll
        for (int e = 0; e < 8; e++) w[e] = (short)kt[(gidx * 8 + e) * 264 + d];
        *(bf16x8*)(dst + gidx * 8) = w;
    }
}

// ---------------------------------------------------------------------------
// Retention scan. One WG per (b,h,vt), vt a 16-wide DV slice.
// grid = 512 (2 blocks/CU), block = 256 (4 waves).
// All MFMA A/B frags except layout-transforms load DIRECTLY from global
// (L1/L2-hot). LDS only for transforms: vsT[v][m] (stride 68),
// pb[c][m] (stride 68), St[v][d] bf16 mirror of S (stride 260).
// Wave w owns state d-band [w*64, w*64+64): Sacc[4] f32x4 (C-layout).
// 2 barriers per chunk. All exp() hoisted out of the loop.
// ---------------------------------------------------------------------------
__global__ __launch_bounds__(256, 2)
void retention(const u16* __restrict__ Q, const u16* __restrict__ Kt,
               const u16* __restrict__ KT, const u16* __restrict__ V,
               u16* __restrict__ O)
{
    __shared__ u16 vsT[16 * 68];
    __shared__ u16 pb[64 * 68];
    __shared__ u16 St[16 * 260];

    const int tid = threadIdx.x;
    const int lane = tid & 63, wave = tid >> 6;
    const int quad = lane >> 4, l16 = lane & 15;
    const int bx = blockIdx.x;
    const int vt = bx & 31, h = (bx >> 5) & 7, b = bx >> 8;

    const float logb = logf(1.0f - exp2f(-5.0f - (float)h));
    const float cdec = __expf(logb * 64.0f);

    // hoisted per-lane constants
    int cr[4];
    float rowe[4], qdecr[4];
#pragma unroll
    for (int r = 0; r < 4; r++) {
        cr[r] = wave * 16 + quad * 4 + r;
        rowe[r]  = __expf(logb * (float)(cr[r] - 63));  // masked-score row factor
        qdecr[r] = rowe[r] * cdec;                      // = exp(logb*(cr+1))
    }
    const int mv = tid >> 2;                 // v-stage source row (0..63)
    const int vc4 = (tid & 3) * 4;           // v-stage 4-col group
    const float kdv = __expf(logb * (float)(63 - mv));

    for (int i = tid; i < 16 * 260; i += 256) St[i] = 0;

    f32x4 Sacc[4];
#pragma unroll
    for (int dt = 0; dt < 4; dt++) Sacc[dt] = (f32x4){0.f, 0.f, 0.f, 0.f};

    const size_t bh = (size_t)(b * 8 + h);

    for (int n = 0; n < 32; n++) {
        const int t0 = n * 64;
        // v loads (registers; pre-barrier)
        u32x2 vv = *(const u32x2*)(V + (size_t)(b * 2048 + t0 + mv) * 4096 + h * 512 + vt * 16 + vc4);

        __syncthreads();   // [A] prev St writes visible; prev vsT/pb reads done

        // stage vs = v * k_dec[m], transposed to [v][m]
        {
            u16 e0 = (u16)(vv[0] & 0xffff), e1 = (u16)(vv[0] >> 16);
            u16 e2 = (u16)(vv[1] & 0xffff), e3 = (u16)(vv[1] >> 16);
            vsT[(vc4 + 0) * 68 + mv] = f2bf(bf2f(e0) * kdv);
            vsT[(vc4 + 1) * 68 + mv] = f2bf(bf2f(e1) * kdv);
            vsT[(vc4 + 2) * 68 + mv] = f2bf(bf2f(e2) * kdv);
            vsT[(vc4 + 3) * 68 + mv] = f2bf(bf2f(e3) * kdv);
        }

        // scores (global q,k frags) + inter (St_{n-1} reads)
        f32x4 sc[4];
        f32x4 oacc = (f32x4){0.f, 0.f, 0.f, 0.f};
#pragma unroll
        for (int i = 0; i < 4; i++) sc[i] = (f32x4){0.f, 0.f, 0.f, 0.f};
        const u16* qrow  = Q  + (size_t)(b * 2048 + t0 + wave * 16 + l16) * 2048 + h * 256 + quad * 8;
        const u16* krow0 = Kt + (size_t)(b * 2048 + t0 + l16) * 2048 + h * 256 + quad * 8;
#pragma unroll
        for (int kc = 0; kc < 8; kc++) {
            bf16x8 af = *(const bf16x8*)(qrow + kc * 32);
            bf16x8 bs = *(const bf16x8*)(St + l16 * 260 + kc * 32 + quad * 8);
            oacc = mfma16(af, bs, oacc);
#pragma unroll
            for (int mt = 0; mt < 4; mt++) {
                bf16x8 bk = *(const bf16x8*)(krow0 + (size_t)mt * 16 * 2048 + kc * 32);
                sc[mt] = mfma16(af, bk, sc[mt]);
            }
        }
        // masked scores -> pb
#pragma unroll
        for (int mt = 0; mt < 4; mt++)
#pragma unroll
            for (int r = 0; r < 4; r++) {
                int m = mt * 16 + l16;
                float val = (cr[r] >= m) ? sc[mt][r] * rowe[r] : 0.0f;
                pb[cr[r] * 68 + m] = f2bf(val);
            }

        __syncthreads();   // [B] vsT/pb visible; all St reads done

        // update: S = S*cdec + kT-frags @ vs   (wave-owned d-band)
#pragma unroll
        for (int dt = 0; dt < 4; dt++)
#pragma unroll
            for (int e = 0; e < 4; e++) Sacc[dt][e] *= cdec;
#pragma unroll
        for (int kc2 = 0; kc2 < 2; kc2++) {
            bf16x8 bv = *(const bf16x8*)(vsT + l16 * 68 + kc2 * 32 + quad * 8);
#pragma unroll
            for (int dt = 0; dt < 4; dt++) {
                bf16x8 ak = *(const bf16x8*)(KT + (bh * 256 + wave * 64 + dt * 16 + l16) * 2048
                                             + t0 + kc2 * 32 + quad * 8);
                Sacc[dt] = mfma16(ak, bv, Sacc[dt]);
            }
        }
        // inter scale + PV
#pragma unroll
        for (int r = 0; r < 4; r++) oacc[r] *= qdecr[r];
#pragma unroll
        for (int kc2 = 0; kc2 < 2; kc2++) {
            bf16x8 ap = *(const bf16x8*)(pb + (wave * 16 + l16) * 68 + kc2 * 32 + quad * 8);
            bf16x8 bv = *(const bf16x8*)(vsT + l16 * 68 + kc2 * 32 + quad * 8);
            oacc = mfma16(ap, bv, oacc);
        }
        // o write
#pragma unroll
        for (int r = 0; r < 4; r++)
            O[(size_t)(b * 2048 + t0 + cr[r]) * 4096 + h * 512 + vt * 16 + l16] = f2bf(oacc[r]);
        // St mirror refresh (S_n) for next chunk's inter
#pragma unroll
        for (int dt = 0; dt < 4; dt++) {
            s16x4 w;
#pragma unroll
            for (int r = 0; r < 4; r++) w[r] = (short)f2bf(Sacc[dt][r]);
            *(s16x4*)(St + l16 * 260 + wave * 64 + dt * 16 + quad * 4) = w;
        }
    }
}

// ---------------------------------------------------------------------------
// RMSNorm over DV=512 per (b,t,h) row, * g_norm_weight(f32), * silu(g).
// grid = 8192 (4 rows/block), block = 256 (1 wave/row).
// ---------------------------------------------------------------------------
__global__ __launch_bounds__(256)
void norm_gate(const u16* __restrict__ O, const u16* __restrict__ G,
               const float* __restrict__ gw, u16* __restrict__ ON)
{
    const int lane = threadIdx.x & 63;
    const size_t row = (size_t)blockIdx.x * 4 + (threadIdx.x >> 6);
    bf16x8 ov = *(const bf16x8*)(O + row * 512 + lane * 8);
    bf16x8 gv = *(const bf16x8*)(G + row * 512 + lane * 8);
    f32x4 w0 = *(const f32x4*)(gw + lane * 8);
    f32x4 w1 = *(const f32x4*)(gw + lane * 8 + 4);
    float of[8], gf[8];
    float ss = 0.f;
#pragma unroll
    for (int j = 0; j < 8; j++) {
        of[j] = bf2f((u16)ov[j]);
        gf[j] = bf2f((u16)gv[j]);
        ss += of[j] * of[j];
    }
#pragma unroll
    for (int off = 32; off > 0; off >>= 1) ss += __shfl_down(ss, off);
    ss = __shfl(ss, 0);
    const float rms = rsqrtf(ss * (1.0f / 512.0f) + 1e-5f);
    bf16x8 res;
#pragma unroll
    for (int j = 0; j < 8; j++) {
        float wj = (j < 4) ? w0[j] : w1[j - 4];
        float xn = of[j] * rms * wj;
        float sg = gf[j] / (1.f + __expf(-gf[j]));
        res[j] = (short)f2bf(xn * sg);
    }
    *(bf16x8*)(ON + row * 512 + lane * 8) = res;
}

// ---------------------------------------------------------------------------
extern "C" void kernel_launch(void* const* d_in, const int* in_sizes, int n_in,
                              void* d_out, int out_size, void* d_ws, size_t ws_size,
                              hipStream_t stream)
{
    const float* x  = (const float*)d_in[0];
    const float* Wq = (const float*)d_in[1];
    const float* Wk = (const float*)d_in[2];
    const float* Wv = (const float*)d_in[3];
    const float* Wg = (const float*)d_in[4];
    const float* Wo = (const float*)d_in[5];
    const float* gw = (const float*)d_in[6];
    float* out = (float*)d_out;

    const size_t M8 = (size_t)4096 * 2048;     // 8.4M u16
    u16* xb = (u16*)d_ws;
    u16* q  = xb + M8;
    u16* k  = q + M8;
    u16* kT = k + M8;
    u16* v  = kT + M8;                         // 16.8M
    u16* o  = v + 2 * M8;                      // 16.8M
    u16* g  = q;                               // alias q+k (dead after retention)
    u16* on = v;                               // alias v (dead after retention)
    u16* wt = kT;                              // weight tmp (pre-rotary)

    dim3 blk(256, 1, 1);
    cvt_bf16<<<dim3(4096, 1, 1), blk, 0, stream>>>(x, xb);

    cvt_bf16<<<dim3(2048, 1, 1), blk, 0, stream>>>(Wq, wt);
    gemm_bt<false><<<dim3(16, 32, 1), blk, 0, stream>>>(xb, wt, q, 2048, 2048);
    cvt_bf16<<<dim3(2048, 1, 1), blk, 0, stream>>>(Wk, wt);
    gemm_bt<false><<<dim3(16, 32, 1), blk, 0, stream>>>(xb, wt, k, 2048, 2048);
    cvt_bf16<<<dim3(4096, 1, 1), blk, 0, stream>>>(Wv, wt);
    gemm_bt<false><<<dim3(32, 32, 1), blk, 0, stream>>>(xb, wt, v, 4096, 2048);

    rotary_qk<<<dim3(512, 1, 1), blk, 0, stream>>>(q, k, kT);
    retention<<<dim3(512, 1, 1), blk, 0, stream>>>(q, k, kT, v, o);

    cvt_bf16<<<dim3(4096, 1, 1), blk, 0, stream>>>(Wg, kT);       // kT dead
    gemm_bt<false><<<dim3(32, 32, 1), blk, 0, stream>>>(xb, kT, g, 4096, 2048);
    norm_gate<<<dim3(8192, 1, 1), blk, 0, stream>>>(o, g, gw, on);
    cvt_bf16<<<dim3(4096, 1, 1), blk, 0, stream>>>(Wo, xb);       // xb dead
    gemm_bt<true><<<dim3(16, 32, 1), blk, 0, stream>>>(on, xb, out, 2048, 4096);
}

// Round 5
// 932.507 us; speedup vs baseline: 1.0092x; 1.0092x over previous
//
#include <hip/hip_runtime.h>

// MultiScaleRetention. Inputs f32, output f32.
// B=2 T=2048 D=2048 H=8 DK=256 DV=512 C=64, N_chunks=32.
// R5: scores hoisted into fused rotary_scores (P global, 4.2MB); retention =
// inter+update+PV only (global A-frags prefetched, LDS B-frags, bank-optimal
// strides, XCD-swizzled grid); projection GEMMs read A=x f32 (convert in
// staging) so xb is dropped.
// ws (u16): P[2.1M] q[8.4M] k[8.4M] kT[8.4M] v[16.8M] o[16.8M] = 121.8MB.
//   weight tmp = kT slot (dead around each use); g aliases q+k; on aliases v.

typedef unsigned short u16;
typedef unsigned int u32;
typedef short bf16x8 __attribute__((ext_vector_type(8)));
typedef short s16x4 __attribute__((ext_vector_type(4)));
typedef float f32x4 __attribute__((ext_vector_type(4)));
typedef u32 u32x2 __attribute__((ext_vector_type(2)));
typedef u32 u32x4 __attribute__((ext_vector_type(4)));

typedef __attribute__((address_space(3))) u32 lds_u32;
typedef __attribute__((address_space(1))) const u32 gbl_u32;

__device__ __forceinline__ float bf2f(u16 u) {
    union { u32 i; float f; } x; x.i = ((u32)u) << 16; return x.f;
}
__device__ __forceinline__ u16 f2bf(float f) {
    union { float f; u32 i; } x; x.f = f;
    u32 u = x.i;
    u += 0x7fffu + ((u >> 16) & 1u);   // RNE (finite only)
    return (u16)(u >> 16);
}
__device__ __forceinline__ f32x4 mfma16(bf16x8 a, bf16x8 b, f32x4 c) {
    return __builtin_amdgcn_mfma_f32_16x16x32_bf16(a, b, c, 0, 0, 0);
}
__device__ __forceinline__ void gload16(const u16* g, u16* lds) {
    __builtin_amdgcn_global_load_lds((gbl_u32*)(unsigned long long)g,
                                     (lds_u32*)(u32)(unsigned long long)lds, 16, 0, 0);
}

// ---------------------------------------------------------------------------
// f32 -> bf16 bulk convert (weights). 8 elems/thread.
// ---------------------------------------------------------------------------
__global__ __launch_bounds__(256)
void cvt_bf16(const float* __restrict__ src, u16* __restrict__ dst)
{
    size_t i = ((size_t)blockIdx.x * 256 + threadIdx.x) * 8;
    f32x4 a = *(const f32x4*)(src + i);
    f32x4 b = *(const f32x4*)(src + i + 4);
    bf16x8 r;
#pragma unroll
    for (int j = 0; j < 4; j++) { r[j] = (short)f2bf(a[j]); r[j + 4] = (short)f2bf(b[j]); }
    *(bf16x8*)(dst + i) = r;
}

// ---------------------------------------------------------------------------
// NT GEMM: C[M][N] = A[M][K] @ B[N][K]^T. A f32 (convert in staging) or bf16
// (DMA). B bf16 via global_load_lds. C bf16 or f32. 128x128 tile, BK=64.
// ---------------------------------------------------------------------------
template<bool AF32, bool CF32>
__global__ __launch_bounds__(256, 2)
void gemm_bt(const void* __restrict__ Av, const u16* __restrict__ Bm,
             void* __restrict__ Cv, int N, int K)
{
    __shared__ u16 Ab[128 * 64];
    __shared__ u16 Bb[128 * 64];
    const int tid = threadIdx.x;
    const int lane = tid & 63, wave = tid >> 6;
    const int quad = lane >> 4, l16 = lane & 15;
    const int tn = blockIdx.x, tm = blockIdx.y;
    const int wr = wave >> 1, wc = wave & 1;

    f32x4 acc[4][4];
#pragma unroll
    for (int i = 0; i < 4; i++)
#pragma unroll
        for (int j = 0; j < 4; j++) acc[i][j] = (f32x4){0.f, 0.f, 0.f, 0.f};

    const float* Af = (const float*)Av + (size_t)tm * 128 * K;
    const u16*   Ah = (const u16*)Av + (size_t)tm * 128 * K;
    const u16* Bbase = Bm + (size_t)tn * 128 * K;
    const int rsub = lane >> 3, csub = (lane & 7) * 8;

    for (int k0 = 0; k0 < K; k0 += 64) {
        f32x4 a0[4], a1[4];
        if constexpr (AF32) {
#pragma unroll
            for (int i = 0; i < 4; i++) {
                int r = (wave * 4 + i) * 8 + rsub;
                const float* ap = Af + (size_t)r * K + k0 + csub;
                a0[i] = *(const f32x4*)ap;
                a1[i] = *(const f32x4*)(ap + 4);
            }
        }
        __syncthreads();                        // readers of prev tile done
#pragma unroll
        for (int i = 0; i < 4; i++) {
            int chunk = wave * 4 + i;
            int r = chunk * 8 + rsub;
            if constexpr (AF32) {
                bf16x8 aw;
#pragma unroll
                for (int j = 0; j < 4; j++) {
                    aw[j]     = (short)f2bf(a0[i][j]);
                    aw[j + 4] = (short)f2bf(a1[i][j]);
                }
                *(bf16x8*)(Ab + chunk * 512 + lane * 8) = aw;
            } else {
                gload16(Ah + (size_t)r * K + k0 + csub, Ab + chunk * 512);
            }
            gload16(Bbase + (size_t)r * K + k0 + csub, Bb + chunk * 512);
        }
        __syncthreads();                        // staging + DMA drained
#pragma unroll
        for (int kc = 0; kc < 2; kc++) {
            bf16x8 af[4], bfr[4];
#pragma unroll
            for (int mt = 0; mt < 4; mt++)
                af[mt] = *(const bf16x8*)(Ab + (wr * 64 + mt * 16 + l16) * 64 + kc * 32 + quad * 8);
#pragma unroll
            for (int nt = 0; nt < 4; nt++)
                bfr[nt] = *(const bf16x8*)(Bb + (wc * 64 + nt * 16 + l16) * 64 + kc * 32 + quad * 8);
#pragma unroll
            for (int mt = 0; mt < 4; mt++)
#pragma unroll
                for (int nt = 0; nt < 4; nt++)
                    acc[mt][nt] = mfma16(af[mt], bfr[nt], acc[mt][nt]);
        }
    }
    const int row0 = tm * 128 + wr * 64 + quad * 4;
    const int col0 = tn * 128 + wc * 64 + l16;
#pragma unroll
    for (int mt = 0; mt < 4; mt++)
#pragma unroll
        for (int nt = 0; nt < 4; nt++)
#pragma unroll
            for (int r = 0; r < 4; r++) {
                size_t idx = (size_t)(row0 + mt * 16 + r) * N + col0 + nt * 16;
                if constexpr (CF32) ((float*)Cv)[idx] = acc[mt][nt][r];
                else                ((u16*)Cv)[idx]   = f2bf(acc[mt][nt][r]);
            }
}

// ---------------------------------------------------------------------------
// Fused rotary + scores + kT. grid = 512 (bx = n*16 + bh, clusters head->XCD),
// block 256 (4 waves). Rotates q (* DK^-0.5, in place) and k (NOT written
// back row-major -- only kT + LDS), computes P[c][m] = mask * (q~ k~^T) *
// exp(logb*(c-63)) into global P[bh][n][64][64], and kT[bh][d][t].
// LDS: qS/kS [64][264] (stride 264: b128 frag reads bank-optimal).
// ---------------------------------------------------------------------------
__global__ __launch_bounds__(256, 2)
void rotary_scores(u16* __restrict__ q, const u16* __restrict__ k,
                   u16* __restrict__ kT, u16* __restrict__ P)
{
    __shared__ u16 qS[64 * 264];
    __shared__ u16 kS[64 * 264];
    const int tid = threadIdx.x;
    const int lane = tid & 63, wave = tid >> 6;
    const int quad = lane >> 4, l16 = lane & 15;
    const int bx = blockIdx.x;
    const int bh = bx & 15, n = bx >> 4;
    const int b = bh >> 3, h = bh & 7;
    const int t0 = n * 64;

    // phase 1: rotary. thread: row=tid>>2, pair-range j0..j0+31.
    const int row = tid >> 2;
    const int j0 = (tid & 3) * 32;
    const size_t rowbase = (size_t)(b * 2048 + t0 + row) * 2048 + h * 256;
    const float tpos = (float)(t0 + row);
#pragma unroll
    for (int i = 0; i < 4; i++) {
        int j = j0 + i * 8;
        bf16x8 x1 = *(const bf16x8*)(q + rowbase + j);
        bf16x8 x2 = *(const bf16x8*)(q + rowbase + j + 128);
        bf16x8 y1 = *(const bf16x8*)(k + rowbase + j);
        bf16x8 y2 = *(const bf16x8*)(k + rowbase + j + 128);
        bf16x8 o1, o2, p1, p2;
#pragma unroll
        for (int e = 0; e < 8; e++) {
            float inv = expf((-9.210340371976184f / 128.f) * (float)(j + e));
            float ang = tpos * inv;
            float sv = sinf(ang), cv = cosf(ang);
            float a = bf2f((u16)x1[e]), bb = bf2f((u16)x2[e]);
            o1[e] = (short)f2bf((a * cv - bb * sv) * 0.0625f);
            o2[e] = (short)f2bf((bb * cv + a * sv) * 0.0625f);
            float e1 = bf2f((u16)y1[e]), e2 = bf2f((u16)y2[e]);
            p1[e] = (short)f2bf(e1 * cv - e2 * sv);
            p2[e] = (short)f2bf(e2 * cv + e1 * sv);
        }
        *(bf16x8*)(q + rowbase + j)       = o1;
        *(bf16x8*)(q + rowbase + j + 128) = o2;
        *(bf16x8*)(qS + row * 264 + j)       = o1;
        *(bf16x8*)(qS + row * 264 + j + 128) = o2;
        *(bf16x8*)(kS + row * 264 + j)       = p1;
        *(bf16x8*)(kS + row * 264 + j + 128) = p2;
    }
    __syncthreads();

    // phase 2: scores. wave handles c-rows [wave*16, +16).
    const float logb = logf(1.0f - exp2f(-5.0f - (float)h));
    f32x4 sc[4];
#pragma unroll
    for (int i = 0; i < 4; i++) sc[i] = (f32x4){0.f, 0.f, 0.f, 0.f};
#pragma unroll
    for (int kc = 0; kc < 8; kc++) {
        bf16x8 af = *(const bf16x8*)(qS + (wave * 16 + l16) * 264 + kc * 32 + quad * 8);
#pragma unroll
        for (int mt = 0; mt < 4; mt++) {
            bf16x8 bk = *(const bf16x8*)(kS + (mt * 16 + l16) * 264 + kc * 32 + quad * 8);
            sc[mt] = mfma16(af, bk, sc[mt]);
        }
    }
    u16* Pb = P + ((size_t)(bh * 32 + n)) * 64 * 64;
#pragma unroll
    for (int r = 0; r < 4; r++) {
        int cr = wave * 16 + quad * 4 + r;
        float rowe = __expf(logb * (float)(cr - 63));
#pragma unroll
        for (int mt = 0; mt < 4; mt++) {
            int m = mt * 16 + l16;
            float val = (cr >= m) ? sc[mt][r] * rowe : 0.0f;
            Pb[cr * 64 + m] = f2bf(val);
        }
    }

    // phase 3: kT transpose (reads kS -- no extra barrier needed, read-only).
    const int d = tid;
    u16* dst = kT + ((size_t)(bh * 256 + d)) * 2048 + t0;
#pragma unroll
    for (int g8 = 0; g8 < 8; g8++) {
        bf16x8 w;
#pragma unroll
        for (int e = 0; e < 8; e++) w[e] = (short)kS[(g8 * 8 + e) * 264 + d];
        *(bf16x8*)(dst + g8 * 8) = w;
    }
}

// ---------------------------------------------------------------------------
// Retention scan (inter + state update + PV only; P precomputed).
// grid = 256 (bx = vt*16 + bh -> head h pinned to XCD h), block 512 (8 waves).
// vt = 32-wide DV slice. Wave roles: cgrp=wave>>1 (o-rows), vhalf=wave&1
// (16-col v half), d-band = [wave*32, +32) for the state update.
// S in fp32 regs (Sacc[2dt][2nt]); bf16 LDS mirror St[32][264]; vsT[32][72].
// A-operands (q, kT, P) prefetched from global pre-barrier. 2 barriers/chunk.
// ---------------------------------------------------------------------------
__global__ __launch_bounds__(512, 2)
void retention(const u16* __restrict__ Q, const u16* __restrict__ KT,
               const u16* __restrict__ V, const u16* __restrict__ P,
               u16* __restrict__ O)
{
    __shared__ u16 St[32 * 264];
    __shared__ u16 vsT[32 * 72];

    const int tid = threadIdx.x;
    const int lane = tid & 63, wave = tid >> 6;
    const int quad = lane >> 4, l16 = lane & 15;
    const int bx = blockIdx.x;
    const int bh = bx & 15, vt = bx >> 4;       // vt < 16 (32-wide slice)
    const int b = bh >> 3, h = bh & 7;
    const int cgrp = wave >> 1, vhalf = wave & 1;

    const float logb = logf(1.0f - exp2f(-5.0f - (float)h));
    const float cdec = __expf(logb * 64.0f);

    int cr[4];
    float qdecr[4];
#pragma unroll
    for (int r = 0; r < 4; r++) {
        cr[r] = cgrp * 16 + quad * 4 + r;
        qdecr[r] = __expf(logb * (float)(cr[r] + 1));
    }
    const int mv = tid >> 3;                 // 0..63 (v-stage source row)
    const int vc4 = (tid & 7) * 4;           // 0..28 (v-stage col group)
    const float kdv = __expf(logb * (float)(63 - mv));

    for (int i = tid; i < 32 * 264; i += 512) St[i] = 0;

    f32x4 Sacc[2][2];       // [dt][nt]; wave d-band rows wave*32+dt*16
#pragma unroll
    for (int dt = 0; dt < 2; dt++)
#pragma unroll
        for (int nt = 0; nt < 2; nt++) Sacc[dt][nt] = (f32x4){0.f, 0.f, 0.f, 0.f};

    for (int n = 0; n < 32; n++) {
        const int t0 = n * 64;
        // ---- global prefetch (pre-barrier; all L2-hot on this XCD) ----
        u32x2 vv = *(const u32x2*)(V + (size_t)(b * 2048 + t0 + mv) * 4096 + h * 512 + vt * 32 + vc4);
        bf16x8 qf[8];
#pragma unroll
        for (int kc = 0; kc < 8; kc++)
            qf[kc] = *(const bf16x8*)(Q + (size_t)(b * 2048 + t0 + cgrp * 16 + l16) * 2048
                                      + h * 256 + kc * 32 + quad * 8);
        bf16x8 ktf[2][2];
#pragma unroll
        for (int dt = 0; dt < 2; dt++)
#pragma unroll
            for (int kc2 = 0; kc2 < 2; kc2++)
                ktf[dt][kc2] = *(const bf16x8*)(KT + (size_t)(bh * 256 + wave * 32 + dt * 16 + l16) * 2048
                                                + t0 + kc2 * 32 + quad * 8);
        bf16x8 pf[2];
#pragma unroll
        for (int kc2 = 0; kc2 < 2; kc2++)
            pf[kc2] = *(const bf16x8*)(P + ((size_t)(bh * 32 + n) * 64 + cgrp * 16 + l16) * 64
                                       + kc2 * 32 + quad * 8);

        __syncthreads();   // [A] prev chunk's LDS reads done; St(n-1) visible

        // stage vsT = v * kdec[m], transposed [v][m]
        {
            u16 e0 = (u16)(vv[0] & 0xffff), e1 = (u16)(vv[0] >> 16);
            u16 e2 = (u16)(vv[1] & 0xffff), e3 = (u16)(vv[1] >> 16);
            vsT[(vc4 + 0) * 72 + mv] = f2bf(bf2f(e0) * kdv);
            vsT[(vc4 + 1) * 72 + mv] = f2bf(bf2f(e1) * kdv);
            vsT[(vc4 + 2) * 72 + mv] = f2bf(bf2f(e2) * kdv);
            vsT[(vc4 + 3) * 72 + mv] = f2bf(bf2f(e3) * kdv);
        }
        // inter: o = q @ S_{n-1}  (reads St)
        f32x4 oacc = (f32x4){0.f, 0.f, 0.f, 0.f};
#pragma unroll
        for (int kc = 0; kc < 8; kc++) {
            bf16x8 bs = *(const bf16x8*)(St + (vhalf * 16 + l16) * 264 + kc * 32 + quad * 8);
            oacc = mfma16(qf[kc], bs, oacc);
        }

        __syncthreads();   // [B] vsT visible; all St reads done

        // update: S = S*cdec + kT @ vs   (wave d-band, both v-halves)
#pragma unroll
        for (int dt = 0; dt < 2; dt++)
#pragma unroll
            for (int nt = 0; nt < 2; nt++)
#pragma unroll
                for (int e = 0; e < 4; e++) Sacc[dt][nt][e] *= cdec;
#pragma unroll
        for (int kc2 = 0; kc2 < 2; kc2++) {
            bf16x8 bv0 = *(const bf16x8*)(vsT + l16 * 72 + kc2 * 32 + quad * 8);
            bf16x8 bv1 = *(const bf16x8*)(vsT + (16 + l16) * 72 + kc2 * 32 + quad * 8);
#pragma unroll
            for (int dt = 0; dt < 2; dt++) {
                Sacc[dt][0] = mfma16(ktf[dt][kc2], bv0, Sacc[dt][0]);
                Sacc[dt][1] = mfma16(ktf[dt][kc2], bv1, Sacc[dt][1]);
            }
        }
        // scale inter by q_dec, add PV
#pragma unroll
        for (int r = 0; r < 4; r++) oacc[r] *= qdecr[r];
#pragma unroll
        for (int kc2 = 0; kc2 < 2; kc2++) {
            bf16x8 bv = *(const bf16x8*)(vsT + (vhalf * 16 + l16) * 72 + kc2 * 32 + quad * 8);
            oacc = mfma16(pf[kc2], bv, oacc);
        }
        // o write
#pragma unroll
        for (int r = 0; r < 4; r++)
            O[(size_t)(b * 2048 + t0 + cr[r]) * 4096 + h * 512 + vt * 32 + vhalf * 16 + l16] =
                f2bf(oacc[r]);
        // St refresh (S_n) for next chunk's inter
#pragma unroll
        for (int dt = 0; dt < 2; dt++)
#pragma unroll
            for (int nt = 0; nt < 2; nt++) {
                s16x4 w;
#pragma unroll
                for (int r = 0; r < 4; r++) w[r] = (short)f2bf(Sacc[dt][nt][r]);
                *(s16x4*)(St + (nt * 16 + l16) * 264 + wave * 32 + dt * 16 + quad * 4) = w;
            }
    }
}

// ---------------------------------------------------------------------------
// RMSNorm over DV=512 per (b,t,h) row, * g_norm_weight(f32), * silu(g).
// grid = 8192 (4 rows/block), block = 256 (1 wave/row).
// ---------------------------------------------------------------------------
__global__ __launch_bounds__(256)
void norm_gate(const u16* __restrict__ O, const u16* __restrict__ G,
               const float* __restrict__ gw, u16* __restrict__ ON)
{
    const int lane = threadIdx.x & 63;
    const size_t row = (size_t)blockIdx.x * 4 + (threadIdx.x >> 6);
    bf16x8 ov = *(const bf16x8*)(O + row * 512 + lane * 8);
    bf16x8 gv = *(const bf16x8*)(G + row * 512 + lane * 8);
    f32x4 w0 = *(const f32x4*)(gw + lane * 8);
    f32x4 w1 = *(const f32x4*)(gw + lane * 8 + 4);
    float of[8], gf[8];
    float ss = 0.f;
#pragma unroll
    for (int j = 0; j < 8; j++) {
        of[j] = bf2f((u16)ov[j]);
        gf[j] = bf2f((u16)gv[j]);
        ss += of[j] * of[j];
    }
#pragma unroll
    for (int off = 32; off > 0; off >>= 1) ss += __shfl_down(ss, off);
    ss = __shfl(ss, 0);
    const float rms = rsqrtf(ss * (1.0f / 512.0f) + 1e-5f);
    bf16x8 res;
#pragma unroll
    for (int j = 0; j < 8; j++) {
        float wj = (j < 4) ? w0[j] : w1[j - 4];
        float xn = of[j] * rms * wj;
        float sg = gf[j] / (1.f + __expf(-gf[j]));
        res[j] = (short)f2bf(xn * sg);
    }
    *(bf16x8*)(ON + row * 512 + lane * 8) = res;
}

// ---------------------------------------------------------------------------
extern "C" void kernel_launch(void* const* d_in, const int* in_sizes, int n_in,
                              void* d_out, int out_size, void* d_ws, size_t ws_size,
                              hipStream_t stream)
{
    const float* x  = (const float*)d_in[0];
    const float* Wq = (const float*)d_in[1];
    const float* Wk = (const float*)d_in[2];
    const float* Wv = (const float*)d_in[3];
    const float* Wg = (const float*)d_in[4];
    const float* Wo = (const float*)d_in[5];
    const float* gw = (const float*)d_in[6];
    float* out = (float*)d_out;

    const size_t M8 = (size_t)4096 * 2048;     // 8.4M u16
    u16* Pb = (u16*)d_ws;                      // 2.1M u16 (16*32*64*64)
    u16* q  = Pb + (size_t)16 * 32 * 64 * 64;
    u16* k  = q + M8;
    u16* kT = k + M8;
    u16* v  = kT + M8;                         // 16.8M
    u16* o  = v + 2 * M8;                      // 16.8M
    u16* g  = q;                               // alias q+k (dead after retention)
    u16* on = v;                               // alias v (dead after retention)
    u16* wt = kT;                              // weight tmp (kT slot, dead around uses)

    dim3 blk(256, 1, 1), blk512(512, 1, 1);
    cvt_bf16<<<dim3(2048, 1, 1), blk, 0, stream>>>(Wq, wt);
    gemm_bt<true, false><<<dim3(16, 32, 1), blk, 0, stream>>>(x, wt, q, 2048, 2048);
    cvt_bf16<<<dim3(2048, 1, 1), blk, 0, stream>>>(Wk, wt);
    gemm_bt<true, false><<<dim3(16, 32, 1), blk, 0, stream>>>(x, wt, k, 2048, 2048);
    cvt_bf16<<<dim3(4096, 1, 1), blk, 0, stream>>>(Wv, wt);
    gemm_bt<true, false><<<dim3(32, 32, 1), blk, 0, stream>>>(x, wt, v, 4096, 2048);

    rotary_scores<<<dim3(512, 1, 1), blk, 0, stream>>>(q, k, kT, Pb);
    retention<<<dim3(256, 1, 1), blk512, 0, stream>>>(q, kT, v, Pb, o);

    cvt_bf16<<<dim3(4096, 1, 1), blk, 0, stream>>>(Wg, kT);       // kT dead
    gemm_bt<true, false><<<dim3(32, 32, 1), blk, 0, stream>>>(x, kT, g, 4096, 2048);
    norm_gate<<<dim3(8192, 1, 1), blk, 0, stream>>>(o, g, gw, on);
    cvt_bf16<<<dim3(4096, 1, 1), blk, 0, stream>>>(Wo, kT);       // Wg-bf16 dead
    gemm_bt<false, true><<<dim3(16, 32, 1), blk, 0, stream>>>(on, kT, out, 2048, 4096);
}

// Round 6
// 694.981 us; speedup vs baseline: 1.3541x; 1.3418x over previous
//
#include <hip/hip_runtime.h>

// MultiScaleRetention. Inputs f32, output f32.
// B=2 T=2048 D=2048 H=8 DK=256 DV=512 C=64, N_chunks=32.
// R6: revert GEMMs to pure-bf16 global_load_lds DMA (R4 style; R5's AF32
// staging cost ~200us). Keep R5 rotary_scores/retention/norm_gate.
// ws (u16): P[2.1M] q[8.4M] k[8.4M] kT[8.4M] v[16.8M] o[16.8M] xb[8.4M]
//   = 138.6MB. g aliases q+k; on aliases v; weight tmp aliases kT.

typedef unsigned short u16;
typedef unsigned int u32;
typedef short bf16x8 __attribute__((ext_vector_type(8)));
typedef short s16x4 __attribute__((ext_vector_type(4)));
typedef float f32x4 __attribute__((ext_vector_type(4)));
typedef u32 u32x2 __attribute__((ext_vector_type(2)));
typedef u32 u32x4 __attribute__((ext_vector_type(4)));

typedef __attribute__((address_space(3))) u32 lds_u32;
typedef __attribute__((address_space(1))) const u32 gbl_u32;

__device__ __forceinline__ float bf2f(u16 u) {
    union { u32 i; float f; } x; x.i = ((u32)u) << 16; return x.f;
}
__device__ __forceinline__ u16 f2bf(float f) {
    union { float f; u32 i; } x; x.f = f;
    u32 u = x.i;
    u += 0x7fffu + ((u >> 16) & 1u);   // RNE (finite only)
    return (u16)(u >> 16);
}
__device__ __forceinline__ f32x4 mfma16(bf16x8 a, bf16x8 b, f32x4 c) {
    return __builtin_amdgcn_mfma_f32_16x16x32_bf16(a, b, c, 0, 0, 0);
}
__device__ __forceinline__ void gload16(const u16* g, u16* lds) {
    __builtin_amdgcn_global_load_lds((gbl_u32*)(unsigned long long)g,
                                     (lds_u32*)(u32)(unsigned long long)lds, 16, 0, 0);
}

// ---------------------------------------------------------------------------
// f32 -> bf16 bulk convert. 8 elems/thread.
// ---------------------------------------------------------------------------
__global__ __launch_bounds__(256)
void cvt_bf16(const float* __restrict__ src, u16* __restrict__ dst)
{
    size_t i = ((size_t)blockIdx.x * 256 + threadIdx.x) * 8;
    f32x4 a = *(const f32x4*)(src + i);
    f32x4 b = *(const f32x4*)(src + i + 4);
    bf16x8 r;
#pragma unroll
    for (int j = 0; j < 4; j++) { r[j] = (short)f2bf(a[j]); r[j + 4] = (short)f2bf(b[j]); }
    *(bf16x8*)(dst + i) = r;
}

// ---------------------------------------------------------------------------
// NT GEMM: C[M][N] = A[M][K](bf16) @ B[N][K](bf16)^T, fp32 acc, C bf16/f32.
// grid=(N/128, M/128), block=256. 128x128 tile, BK=64, global_load_lds DMA.
// ---------------------------------------------------------------------------
template<bool CF32>
__global__ __launch_bounds__(256, 2)
void gemm_bt(const u16* __restrict__ A, const u16* __restrict__ Bm,
             void* __restrict__ Cv, int N, int K)
{
    __shared__ u16 Ab[128 * 64];
    __shared__ u16 Bb[128 * 64];
    const int tid = threadIdx.x;
    const int lane = tid & 63, wave = tid >> 6;
    const int quad = lane >> 4, l16 = lane & 15;
    const int tn = blockIdx.x, tm = blockIdx.y;
    const int wr = wave >> 1, wc = wave & 1;

    f32x4 acc[4][4];
#pragma unroll
    for (int i = 0; i < 4; i++)
#pragma unroll
        for (int j = 0; j < 4; j++) acc[i][j] = (f32x4){0.f, 0.f, 0.f, 0.f};

    const u16* Abase = A + (size_t)tm * 128 * K;
    const u16* Bbase = Bm + (size_t)tn * 128 * K;
    const int rsub = lane >> 3, csub = (lane & 7) * 8;

    for (int k0 = 0; k0 < K; k0 += 64) {
        __syncthreads();                        // readers of prev tile done
#pragma unroll
        for (int i = 0; i < 4; i++) {
            int chunk = wave * 4 + i;           // 16 chunks of 8 rows x 64 cols
            int r = chunk * 8 + rsub;
            gload16(Abase + (size_t)r * K + k0 + csub, Ab + chunk * 512);
            gload16(Bbase + (size_t)r * K + k0 + csub, Bb + chunk * 512);
        }
        __syncthreads();                        // DMA drained (vmcnt0 at barrier)
#pragma unroll
        for (int kc = 0; kc < 2; kc++) {
            bf16x8 af[4], bfr[4];
#pragma unroll
            for (int mt = 0; mt < 4; mt++)
                af[mt] = *(const bf16x8*)(Ab + (wr * 64 + mt * 16 + l16) * 64 + kc * 32 + quad * 8);
#pragma unroll
            for (int nt = 0; nt < 4; nt++)
                bfr[nt] = *(const bf16x8*)(Bb + (wc * 64 + nt * 16 + l16) * 64 + kc * 32 + quad * 8);
#pragma unroll
            for (int mt = 0; mt < 4; mt++)
#pragma unroll
                for (int nt = 0; nt < 4; nt++)
                    acc[mt][nt] = mfma16(af[mt], bfr[nt], acc[mt][nt]);
        }
    }
    const int row0 = tm * 128 + wr * 64 + quad * 4;
    const int col0 = tn * 128 + wc * 64 + l16;
#pragma unroll
    for (int mt = 0; mt < 4; mt++)
#pragma unroll
        for (int nt = 0; nt < 4; nt++)
#pragma unroll
            for (int r = 0; r < 4; r++) {
                size_t idx = (size_t)(row0 + mt * 16 + r) * N + col0 + nt * 16;
                if constexpr (CF32) ((float*)Cv)[idx] = acc[mt][nt][r];
                else                ((u16*)Cv)[idx]   = f2bf(acc[mt][nt][r]);
            }
}

// ---------------------------------------------------------------------------
// Fused rotary + scores + kT. grid = 512 (bx = n*16 + bh), block 256.
// Rotates q (* DK^-0.5, in place); k rotated into LDS only; emits
// P[bh][n][64][64] = mask * (q~ k~^T) * exp(logb*(c-63)) and kT[bh][d][t].
// LDS: qS/kS [64][264].
// ---------------------------------------------------------------------------
__global__ __launch_bounds__(256, 2)
void rotary_scores(u16* __restrict__ q, const u16* __restrict__ k,
                   u16* __restrict__ kT, u16* __restrict__ P)
{
    __shared__ u16 qS[64 * 264];
    __shared__ u16 kS[64 * 264];
    const int tid = threadIdx.x;
    const int lane = tid & 63, wave = tid >> 6;
    const int quad = lane >> 4, l16 = lane & 15;
    const int bx = blockIdx.x;
    const int bh = bx & 15, n = bx >> 4;
    const int b = bh >> 3, h = bh & 7;
    const int t0 = n * 64;

    // phase 1: rotary. thread: row=tid>>2, pair-range j0..j0+31.
    const int row = tid >> 2;
    const int j0 = (tid & 3) * 32;
    const size_t rowbase = (size_t)(b * 2048 + t0 + row) * 2048 + h * 256;
    const float tpos = (float)(t0 + row);
#pragma unroll
    for (int i = 0; i < 4; i++) {
        int j = j0 + i * 8;
        bf16x8 x1 = *(const bf16x8*)(q + rowbase + j);
        bf16x8 x2 = *(const bf16x8*)(q + rowbase + j + 128);
        bf16x8 y1 = *(const bf16x8*)(k + rowbase + j);
        bf16x8 y2 = *(const bf16x8*)(k + rowbase + j + 128);
        bf16x8 o1, o2, p1, p2;
#pragma unroll
        for (int e = 0; e < 8; e++) {
            float inv = expf((-9.210340371976184f / 128.f) * (float)(j + e));
            float ang = tpos * inv;
            float sv = sinf(ang), cv = cosf(ang);
            float a = bf2f((u16)x1[e]), bb = bf2f((u16)x2[e]);
            o1[e] = (short)f2bf((a * cv - bb * sv) * 0.0625f);
            o2[e] = (short)f2bf((bb * cv + a * sv) * 0.0625f);
            float e1 = bf2f((u16)y1[e]), e2 = bf2f((u16)y2[e]);
            p1[e] = (short)f2bf(e1 * cv - e2 * sv);
            p2[e] = (short)f2bf(e2 * cv + e1 * sv);
        }
        *(bf16x8*)(q + rowbase + j)       = o1;
        *(bf16x8*)(q + rowbase + j + 128) = o2;
        *(bf16x8*)(qS + row * 264 + j)       = o1;
        *(bf16x8*)(qS + row * 264 + j + 128) = o2;
        *(bf16x8*)(kS + row * 264 + j)       = p1;
        *(bf16x8*)(kS + row * 264 + j + 128) = p2;
    }
    __syncthreads();

    // phase 2: scores. wave handles c-rows [wave*16, +16).
    const float logb = logf(1.0f - exp2f(-5.0f - (float)h));
    f32x4 sc[4];
#pragma unroll
    for (int i = 0; i < 4; i++) sc[i] = (f32x4){0.f, 0.f, 0.f, 0.f};
#pragma unroll
    for (int kc = 0; kc < 8; kc++) {
        bf16x8 af = *(const bf16x8*)(qS + (wave * 16 + l16) * 264 + kc * 32 + quad * 8);
#pragma unroll
        for (int mt = 0; mt < 4; mt++) {
            bf16x8 bk = *(const bf16x8*)(kS + (mt * 16 + l16) * 264 + kc * 32 + quad * 8);
            sc[mt] = mfma16(af, bk, sc[mt]);
        }
    }
    u16* Pb = P + ((size_t)(bh * 32 + n)) * 64 * 64;
#pragma unroll
    for (int r = 0; r < 4; r++) {
        int cr = wave * 16 + quad * 4 + r;
        float rowe = __expf(logb * (float)(cr - 63));
#pragma unroll
        for (int mt = 0; mt < 4; mt++) {
            int m = mt * 16 + l16;
            float val = (cr >= m) ? sc[mt][r] * rowe : 0.0f;
            Pb[cr * 64 + m] = f2bf(val);
        }
    }

    // phase 3: kT transpose (reads kS; read-only after barrier).
    const int d = tid;
    u16* dst = kT + ((size_t)(bh * 256 + d)) * 2048 + t0;
#pragma unroll
    for (int g8 = 0; g8 < 8; g8++) {
        bf16x8 w;
#pragma unroll
        for (int e = 0; e < 8; e++) w[e] = (short)kS[(g8 * 8 + e) * 264 + d];
        *(bf16x8*)(dst + g8 * 8) = w;
    }
}

// ---------------------------------------------------------------------------
// Retention scan (inter + state update + PV; P precomputed).
// grid = 256 (bx = vt*16 + bh), block 512 (8 waves).
// vt = 32-wide DV slice. cgrp=wave>>1 (o-rows), vhalf=wave&1, d-band wave*32.
// S in fp32 regs; bf16 LDS mirror St[32][264]; vsT[32][72].
// A-operands (q, kT, P) prefetched from global pre-barrier. 2 barriers/chunk.
// ---------------------------------------------------------------------------
__global__ __launch_bounds__(512, 2)
void retention(const u16* __restrict__ Q, const u16* __restrict__ KT,
               const u16* __restrict__ V, const u16* __restrict__ P,
               u16* __restrict__ O)
{
    __shared__ u16 St[32 * 264];
    __shared__ u16 vsT[32 * 72];

    const int tid = threadIdx.x;
    const int lane = tid & 63, wave = tid >> 6;
    const int quad = lane >> 4, l16 = lane & 15;
    const int bx = blockIdx.x;
    const int bh = bx & 15, vt = bx >> 4;
    const int b = bh >> 3, h = bh & 7;
    const int cgrp = wave >> 1, vhalf = wave & 1;

    const float logb = logf(1.0f - exp2f(-5.0f - (float)h));
    const float cdec = __expf(logb * 64.0f);

    int cr[4];
    float qdecr[4];
#pragma unroll
    for (int r = 0; r < 4; r++) {
        cr[r] = cgrp * 16 + quad * 4 + r;
        qdecr[r] = __expf(logb * (float)(cr[r] + 1));
    }
    const int mv = tid >> 3;
    const int vc4 = (tid & 7) * 4;
    const float kdv = __expf(logb * (float)(63 - mv));

    for (int i = tid; i < 32 * 264; i += 512) St[i] = 0;

    f32x4 Sacc[2][2];
#pragma unroll
    for (int dt = 0; dt < 2; dt++)
#pragma unroll
        for (int nt = 0; nt < 2; nt++) Sacc[dt][nt] = (f32x4){0.f, 0.f, 0.f, 0.f};

    for (int n = 0; n < 32; n++) {
        const int t0 = n * 64;
        // ---- global prefetch (pre-barrier) ----
        u32x2 vv = *(const u32x2*)(V + (size_t)(b * 2048 + t0 + mv) * 4096 + h * 512 + vt * 32 + vc4);
        bf16x8 qf[8];
#pragma unroll
        for (int kc = 0; kc < 8; kc++)
            qf[kc] = *(const bf16x8*)(Q + (size_t)(b * 2048 + t0 + cgrp * 16 + l16) * 2048
                                      + h * 256 + kc * 32 + quad * 8);
        bf16x8 ktf[2][2];
#pragma unroll
        for (int dt = 0; dt < 2; dt++)
#pragma unroll
            for (int kc2 = 0; kc2 < 2; kc2++)
                ktf[dt][kc2] = *(const bf16x8*)(KT + (size_t)(bh * 256 + wave * 32 + dt * 16 + l16) * 2048
                                                + t0 + kc2 * 32 + quad * 8);
        bf16x8 pf[2];
#pragma unroll
        for (int kc2 = 0; kc2 < 2; kc2++)
            pf[kc2] = *(const bf16x8*)(P + ((size_t)(bh * 32 + n) * 64 + cgrp * 16 + l16) * 64
                                       + kc2 * 32 + quad * 8);

        __syncthreads();   // [A] prev chunk's LDS reads done; St(n-1) visible

        // stage vsT = v * kdec[m], transposed [v][m]
        {
            u16 e0 = (u16)(vv[0] & 0xffff), e1 = (u16)(vv[0] >> 16);
            u16 e2 = (u16)(vv[1] & 0xffff), e3 = (u16)(vv[1] >> 16);
            vsT[(vc4 + 0) * 72 + mv] = f2bf(bf2f(e0) * kdv);
            vsT[(vc4 + 1) * 72 + mv] = f2bf(bf2f(e1) * kdv);
            vsT[(vc4 + 2) * 72 + mv] = f2bf(bf2f(e2) * kdv);
            vsT[(vc4 + 3) * 72 + mv] = f2bf(bf2f(e3) * kdv);
        }
        // inter: o = q @ S_{n-1}
        f32x4 oacc = (f32x4){0.f, 0.f, 0.f, 0.f};
#pragma unroll
        for (int kc = 0; kc < 8; kc++) {
            bf16x8 bs = *(const bf16x8*)(St + (vhalf * 16 + l16) * 264 + kc * 32 + quad * 8);
            oacc = mfma16(qf[kc], bs, oacc);
        }

        __syncthreads();   // [B] vsT visible; all St reads done

        // update: S = S*cdec + kT @ vs
#pragma unroll
        for (int dt = 0; dt < 2; dt++)
#pragma unroll
            for (int nt = 0; nt < 2; nt++)
#pragma unroll
                for (int e = 0; e < 4; e++) Sacc[dt][nt][e] *= cdec;
#pragma unroll
        for (int kc2 = 0; kc2 < 2; kc2++) {
            bf16x8 bv0 = *(const bf16x8*)(vsT + l16 * 72 + kc2 * 32 + quad * 8);
            bf16x8 bv1 = *(const bf16x8*)(vsT + (16 + l16) * 72 + kc2 * 32 + quad * 8);
#pragma unroll
            for (int dt = 0; dt < 2; dt++) {
                Sacc[dt][0] = mfma16(ktf[dt][kc2], bv0, Sacc[dt][0]);
                Sacc[dt][1] = mfma16(ktf[dt][kc2], bv1, Sacc[dt][1]);
            }
        }
        // scale inter by q_dec, add PV
#pragma unroll
        for (int r = 0; r < 4; r++) oacc[r] *= qdecr[r];
#pragma unroll
        for (int kc2 = 0; kc2 < 2; kc2++) {
            bf16x8 bv = *(const bf16x8*)(vsT + (vhalf * 16 + l16) * 72 + kc2 * 32 + quad * 8);
            oacc = mfma16(pf[kc2], bv, oacc);
        }
        // o write
#pragma unroll
        for (int r = 0; r < 4; r++)
            O[(size_t)(b * 2048 + t0 + cr[r]) * 4096 + h * 512 + vt * 32 + vhalf * 16 + l16] =
                f2bf(oacc[r]);
        // St refresh (S_n)
#pragma unroll
        for (int dt = 0; dt < 2; dt++)
#pragma unroll
            for (int nt = 0; nt < 2; nt++) {
                s16x4 w;
#pragma unroll
                for (int r = 0; r < 4; r++) w[r] = (short)f2bf(Sacc[dt][nt][r]);
                *(s16x4*)(St + (nt * 16 + l16) * 264 + wave * 32 + dt * 16 + quad * 4) = w;
            }
    }
}

// ---------------------------------------------------------------------------
// RMSNorm over DV=512 per (b,t,h) row, * g_norm_weight(f32), * silu(g).
// grid = 8192 (4 rows/block), block = 256 (1 wave/row).
// ---------------------------------------------------------------------------
__global__ __launch_bounds__(256)
void norm_gate(const u16* __restrict__ O, const u16* __restrict__ G,
               const float* __restrict__ gw, u16* __restrict__ ON)
{
    const int lane = threadIdx.x & 63;
    const size_t row = (size_t)blockIdx.x * 4 + (threadIdx.x >> 6);
    bf16x8 ov = *(const bf16x8*)(O + row * 512 + lane * 8);
    bf16x8 gv = *(const bf16x8*)(G + row * 512 + lane * 8);
    f32x4 w0 = *(const f32x4*)(gw + lane * 8);
    f32x4 w1 = *(const f32x4*)(gw + lane * 8 + 4);
    float of[8], gf[8];
    float ss = 0.f;
#pragma unroll
    for (int j = 0; j < 8; j++) {
        of[j] = bf2f((u16)ov[j]);
        gf[j] = bf2f((u16)gv[j]);
        ss += of[j] * of[j];
    }
#pragma unroll
    for (int off = 32; off > 0; off >>= 1) ss += __shfl_down(ss, off);
    ss = __shfl(ss, 0);
    const float rms = rsqrtf(ss * (1.0f / 512.0f) + 1e-5f);
    bf16x8 res;
#pragma unroll
    for (int j = 0; j < 8; j++) {
        float wj = (j < 4) ? w0[j] : w1[j - 4];
        float xn = of[j] * rms * wj;
        float sg = gf[j] / (1.f + __expf(-gf[j]));
        res[j] = (short)f2bf(xn * sg);
    }
    *(bf16x8*)(ON + row * 512 + lane * 8) = res;
}

// ---------------------------------------------------------------------------
extern "C" void kernel_launch(void* const* d_in, const int* in_sizes, int n_in,
                              void* d_out, int out_size, void* d_ws, size_t ws_size,
                              hipStream_t stream)
{
    const float* x  = (const float*)d_in[0];
    const float* Wq = (const float*)d_in[1];
    const float* Wk = (const float*)d_in[2];
    const float* Wv = (const float*)d_in[3];
    const float* Wg = (const float*)d_in[4];
    const float* Wo = (const float*)d_in[5];
    const float* gw = (const float*)d_in[6];
    float* out = (float*)d_out;

    const size_t M8 = (size_t)4096 * 2048;     // 8.4M u16
    u16* Pb = (u16*)d_ws;                      // 2.1M u16
    u16* q  = Pb + (size_t)16 * 32 * 64 * 64;
    u16* k  = q + M8;
    u16* kT = k + M8;
    u16* v  = kT + M8;                         // 16.8M
    u16* o  = v + 2 * M8;                      // 16.8M
    u16* xb = o + 2 * M8;                      // 8.4M
    u16* g  = q;                               // alias q+k (dead after retention)
    u16* on = v;                               // alias v (dead after retention)
    u16* wt = kT;                              // weight tmp (kT slot)

    dim3 blk(256, 1, 1), blk512(512, 1, 1);
    cvt_bf16<<<dim3(4096, 1, 1), blk, 0, stream>>>(x, xb);

    cvt_bf16<<<dim3(2048, 1, 1), blk, 0, stream>>>(Wq, wt);
    gemm_bt<false><<<dim3(16, 32, 1), blk, 0, stream>>>(xb, wt, q, 2048, 2048);
    cvt_bf16<<<dim3(2048, 1, 1), blk, 0, stream>>>(Wk, wt);
    gemm_bt<false><<<dim3(16, 32, 1), blk, 0, stream>>>(xb, wt, k, 2048, 2048);
    cvt_bf16<<<dim3(4096, 1, 1), blk, 0, stream>>>(Wv, wt);
    gemm_bt<false><<<dim3(32, 32, 1), blk, 0, stream>>>(xb, wt, v, 4096, 2048);

    rotary_scores<<<dim3(512, 1, 1), blk, 0, stream>>>(q, k, kT, Pb);
    retention<<<dim3(256, 1, 1), blk512, 0, stream>>>(q, kT, v, Pb, o);

    cvt_bf16<<<dim3(4096, 1, 1), blk, 0, stream>>>(Wg, kT);       // kT dead
    gemm_bt<false><<<dim3(32, 32, 1), blk, 0, stream>>>(xb, kT, g, 4096, 2048);
    norm_gate<<<dim3(8192, 1, 1), blk, 0, stream>>>(o, g, gw, on);
    cvt_bf16<<<dim3(4096, 1, 1), blk, 0, stream>>>(Wo, kT);
    gemm_bt<true><<<dim3(16, 32, 1), blk, 0, stream>>>(on, kT, out, 2048, 4096);
}